// Round 1
// baseline (320.344 us; speedup 1.0000x reference)
//
#include <hip/hip_runtime.h>
#include <math.h>

#define NN 20000
#define NE 640000
#define HID 128
#define NH 8
#define HD 16
#define ATT_SCALE 0.25f

// ============================ CSR build ============================
__global__ __launch_bounds__(256) void k_hist(const int* __restrict__ dst,
                                              int* __restrict__ cnt) {
  int e = blockIdx.x * 256 + threadIdx.x;
  if (e < NE) atomicAdd(&cnt[dst[e]], 1);
}

__global__ __launch_bounds__(256) void k_scan_a(const int* __restrict__ cnt,
                                                int* __restrict__ off,
                                                int* __restrict__ bsums) {
  __shared__ int a[256], b[256];
  int t = threadIdx.x;
  int i = blockIdx.x * 256 + t;
  int v = (i < NN) ? cnt[i] : 0;
  a[t] = v;
  __syncthreads();
  int* s = a;
  int* d = b;
  for (int st = 1; st < 256; st <<= 1) {
    d[t] = s[t] + (t >= st ? s[t - st] : 0);
    __syncthreads();
    int* tp = s; s = d; d = tp;
  }
  if (i < NN) off[i] = s[t] - v;  // exclusive within block
  if (t == 255) bsums[blockIdx.x] = s[t];
}

__global__ __launch_bounds__(128) void k_scan_b(int* __restrict__ bsums, int nb) {
  __shared__ int a[128], b[128];
  int t = threadIdx.x;
  int v = (t < nb) ? bsums[t] : 0;
  a[t] = v;
  __syncthreads();
  int* s = a;
  int* d = b;
  for (int st = 1; st < 128; st <<= 1) {
    d[t] = s[t] + (t >= st ? s[t - st] : 0);
    __syncthreads();
    int* tp = s; s = d; d = tp;
  }
  if (t < nb) bsums[t] = s[t] - v;  // exclusive
}

__global__ __launch_bounds__(256) void k_scan_c(int* __restrict__ off,
                                                const int* __restrict__ bsums,
                                                int* __restrict__ cur) {
  int i = blockIdx.x * 256 + threadIdx.x;
  if (i < NN) {
    int o = off[i] + bsums[blockIdx.x];
    off[i] = o;
    cur[i] = o;
  }
  if (i == 0) off[NN] = NE;
}

__global__ __launch_bounds__(256) void k_scatter(const int* __restrict__ src,
                                                 const int* __restrict__ dst,
                                                 int* __restrict__ cur,
                                                 int* __restrict__ srcs) {
  int e = blockIdx.x * 256 + threadIdx.x;
  if (e < NE) {
    int d = dst[e];
    int p = atomicAdd(&cur[d], 1);
    srcs[p] = src[e];
  }
}

// ============================ f32 GEMM: O = X @ W^T + B ============================
// X: [NN,128], W: [128,128] row-major (out-col c uses W[c][:]), B: [128]
// block = 256 threads, tile = 64 rows x 128 cols, k-chunked by 32.
// thread (cg = t&15, rg = t>>4) computes rows rg*4+i (i<4), cols cg+16*j (j<8).
__device__ __forceinline__ void gemm_xwt(const float* __restrict__ X,
                                         const float* __restrict__ W,
                                         const float* __restrict__ B,
                                         float* __restrict__ O, int row0) {
  __shared__ float xs[64][36];   // +4 pad: float4-aligned, 2-way banks (free)
  __shared__ float wl[128][36];
  int t = threadIdx.x;
  int cg = t & 15;
  int rg = t >> 4;
  float acc[4][8] = {};
  for (int kb = 0; kb < 128; kb += 32) {
    __syncthreads();
#pragma unroll
    for (int j = 0; j < 2; ++j) {  // stage X chunk: 64x32 = 512 float4
      int f = j * 256 + t;
      int r = f >> 3, k4 = (f & 7) * 4;
      int gr = row0 + r;
      float4 v = make_float4(0.f, 0.f, 0.f, 0.f);
      if (gr < NN) v = *(const float4*)(X + gr * HID + kb + k4);
      *(float4*)(&xs[r][k4]) = v;
    }
#pragma unroll
    for (int j = 0; j < 4; ++j) {  // stage W chunk: 128x32 = 1024 float4
      int f = j * 256 + t;
      int c = f >> 3, k4 = (f & 7) * 4;
      *(float4*)(&wl[c][k4]) = *(const float4*)(W + c * HID + kb + k4);
    }
    __syncthreads();
#pragma unroll
    for (int k4 = 0; k4 < 32; k4 += 4) {
      float4 xv[4], wv[8];
#pragma unroll
      for (int i = 0; i < 4; ++i) xv[i] = *(const float4*)(&xs[rg * 4 + i][k4]);
#pragma unroll
      for (int j = 0; j < 8; ++j) wv[j] = *(const float4*)(&wl[cg + 16 * j][k4]);
#pragma unroll
      for (int i = 0; i < 4; ++i)
#pragma unroll
        for (int j = 0; j < 8; ++j)
          acc[i][j] += xv[i].x * wv[j].x + xv[i].y * wv[j].y +
                       xv[i].z * wv[j].z + xv[i].w * wv[j].w;
    }
  }
#pragma unroll
  for (int i = 0; i < 4; ++i) {
    int gr = row0 + rg * 4 + i;
    if (gr < NN) {
#pragma unroll
      for (int j = 0; j < 8; ++j) {
        int c = cg + 16 * j;
        O[gr * HID + c] = acc[i][j] + B[c];
      }
    }
  }
}

__global__ __launch_bounds__(256) void k_proj(
    const float* __restrict__ q, const float* __restrict__ k,
    const float* __restrict__ v, const float* __restrict__ Wq,
    const float* __restrict__ bq, const float* __restrict__ Wk,
    const float* __restrict__ bk, const float* __restrict__ Wv,
    const float* __restrict__ bv, float* __restrict__ Q, float* __restrict__ K,
    float* __restrict__ V) {
  int row0 = blockIdx.x * 64;
  if (blockIdx.y == 0) gemm_xwt(q, Wq, bq, Q, row0);
  else if (blockIdx.y == 1) gemm_xwt(k, Wk, bk, K, row0);
  else gemm_xwt(v, Wv, bv, V, row0);
}

__global__ __launch_bounds__(256) void k_gemm(const float* __restrict__ X,
                                              const float* __restrict__ W,
                                              const float* __restrict__ B,
                                              float* __restrict__ O) {
  gemm_xwt(X, W, B, O, blockIdx.x * 64);
}

// ============================ edge attention ============================
// one thread per (node, head); 8 adjacent lanes = 8 heads of one node
__global__ __launch_bounds__(256) void k_edge(const int* __restrict__ off,
                                              const int* __restrict__ srcs,
                                              const float* __restrict__ Q,
                                              const float* __restrict__ K,
                                              const float* __restrict__ V,
                                              float* __restrict__ O) {
  int gid = blockIdx.x * 256 + threadIdx.x;
  if (gid >= NN * NH) return;
  int node = gid >> 3;
  int h = gid & 7;
  const float* qp = Q + node * HID + h * HD;
  float4 q0 = *(const float4*)(qp);
  float4 q1 = *(const float4*)(qp + 4);
  float4 q2 = *(const float4*)(qp + 8);
  float4 q3 = *(const float4*)(qp + 12);
  int i0 = off[node], i1 = off[node + 1];
  float m = -INFINITY, l = 0.f;
  float4 a0 = make_float4(0.f, 0.f, 0.f, 0.f);
  float4 a1 = a0, a2 = a0, a3 = a0;
  for (int i = i0; i < i1; ++i) {
    int s = srcs[i];
    const float* kp = K + s * HID + h * HD;
    float4 k0 = *(const float4*)(kp);
    float4 k1 = *(const float4*)(kp + 4);
    float4 k2 = *(const float4*)(kp + 8);
    float4 k3 = *(const float4*)(kp + 12);
    float dt = q0.x * k0.x + q0.y * k0.y + q0.z * k0.z + q0.w * k0.w +
               q1.x * k1.x + q1.y * k1.y + q1.z * k1.z + q1.w * k1.w +
               q2.x * k2.x + q2.y * k2.y + q2.z * k2.z + q2.w * k2.w +
               q3.x * k3.x + q3.y * k3.y + q3.z * k3.z + q3.w * k3.w;
    float sc = dt * ATT_SCALE;
    float nm = fmaxf(m, sc);
    float corr = __expf(m - nm);  // m=-inf first iter -> 0
    float p = __expf(sc - nm);
    m = nm;
    l = l * corr + p;
    const float* vp = V + s * HID + h * HD;
    float4 v0 = *(const float4*)(vp);
    float4 v1 = *(const float4*)(vp + 4);
    float4 v2 = *(const float4*)(vp + 8);
    float4 v3 = *(const float4*)(vp + 12);
    a0.x = a0.x * corr + p * v0.x; a0.y = a0.y * corr + p * v0.y;
    a0.z = a0.z * corr + p * v0.z; a0.w = a0.w * corr + p * v0.w;
    a1.x = a1.x * corr + p * v1.x; a1.y = a1.y * corr + p * v1.y;
    a1.z = a1.z * corr + p * v1.z; a1.w = a1.w * corr + p * v1.w;
    a2.x = a2.x * corr + p * v2.x; a2.y = a2.y * corr + p * v2.y;
    a2.z = a2.z * corr + p * v2.z; a2.w = a2.w * corr + p * v2.w;
    a3.x = a3.x * corr + p * v3.x; a3.y = a3.y * corr + p * v3.y;
    a3.z = a3.z * corr + p * v3.z; a3.w = a3.w * corr + p * v3.w;
  }
  float inv = 1.f / (l + 1e-8f);  // degree 0 -> acc 0 -> out 0 (matches ref)
  float* op = O + node * HID + h * HD;
  a0.x *= inv; a0.y *= inv; a0.z *= inv; a0.w *= inv;
  a1.x *= inv; a1.y *= inv; a1.z *= inv; a1.w *= inv;
  a2.x *= inv; a2.y *= inv; a2.z *= inv; a2.w *= inv;
  a3.x *= inv; a3.y *= inv; a3.z *= inv; a3.w *= inv;
  *(float4*)(op) = a0;
  *(float4*)(op + 4) = a1;
  *(float4*)(op + 8) = a2;
  *(float4*)(op + 12) = a3;
}

// ============================ launch ============================
extern "C" void kernel_launch(void* const* d_in, const int* in_sizes, int n_in,
                              void* d_out, int out_size, void* d_ws,
                              size_t ws_size, hipStream_t stream) {
  const float* q = (const float*)d_in[0];
  const float* k = (const float*)d_in[1];
  const float* v = (const float*)d_in[2];
  const int* ei = (const int*)d_in[3];
  const float* Wq = (const float*)d_in[4];
  const float* bq = (const float*)d_in[5];
  const float* Wk = (const float*)d_in[6];
  const float* bk = (const float*)d_in[7];
  const float* Wv = (const float*)d_in[8];
  const float* bv = (const float*)d_in[9];
  const float* Wo = (const float*)d_in[10];
  const float* bo = (const float*)d_in[11];
  const int* src = ei;
  const int* dst = ei + NE;

  int* cnt = (int*)d_ws;            // NN
  int* off = cnt + NN;              // NN + 4 (padded)
  int* cur = off + NN + 4;          // NN
  int* bsums = cur + NN;            // 128
  int* srcs = bsums + 128;          // NE
  float* Q = (float*)(srcs + NE);   // NN*HID
  float* K = Q + NN * HID;
  float* V = K + NN * HID;
  float* O = (float*)d_out;

  hipMemsetAsync(cnt, 0, NN * sizeof(int), stream);
  k_hist<<<(NE + 255) / 256, 256, 0, stream>>>(dst, cnt);
  int nb = (NN + 255) / 256;  // 79
  k_scan_a<<<nb, 256, 0, stream>>>(cnt, off, bsums);
  k_scan_b<<<1, 128, 0, stream>>>(bsums, nb);
  k_scan_c<<<nb, 256, 0, stream>>>(off, bsums, cur);
  k_scatter<<<(NE + 255) / 256, 256, 0, stream>>>(src, dst, cur, srcs);

  dim3 pg((NN + 63) / 64, 3);
  k_proj<<<pg, 256, 0, stream>>>(q, k, v, Wq, bq, Wk, bk, Wv, bv, Q, K, V);
  k_edge<<<(NN * NH + 255) / 256, 256, 0, stream>>>(off, srcs, Q, K, V, O);
  k_gemm<<<(NN + 63) / 64, 256, 0, stream>>>(O, Wo, bo, O);  // in-place safe: block-private rows, full cols
}

// Round 2
// 244.922 us; speedup vs baseline: 1.3079x; 1.3079x over previous
//
#include <hip/hip_runtime.h>
#include <math.h>

#define NN 20000
#define NE 640000
#define HID 128
#define NH 8
#define HD 16
#define ATT_SCALE 0.25f

typedef __attribute__((ext_vector_type(8))) short bhalf8;
typedef __attribute__((ext_vector_type(4))) float floatx4;

// ============================ CSR build ============================
__global__ __launch_bounds__(256) void k_hist(const int* __restrict__ dst,
                                              int* __restrict__ cnt) {
  int e = blockIdx.x * 256 + threadIdx.x;
  if (e < NE) atomicAdd(&cnt[dst[e]], 1);
}

__global__ __launch_bounds__(256) void k_scan_a(const int* __restrict__ cnt,
                                                int* __restrict__ off,
                                                int* __restrict__ bsums) {
  __shared__ int a[256], b[256];
  int t = threadIdx.x;
  int i = blockIdx.x * 256 + t;
  int v = (i < NN) ? cnt[i] : 0;
  a[t] = v;
  __syncthreads();
  int* s = a;
  int* d = b;
  for (int st = 1; st < 256; st <<= 1) {
    d[t] = s[t] + (t >= st ? s[t - st] : 0);
    __syncthreads();
    int* tp = s; s = d; d = tp;
  }
  if (i < NN) off[i] = s[t] - v;  // exclusive within block
  if (t == 255) bsums[blockIdx.x] = s[t];
}

__global__ __launch_bounds__(128) void k_scan_b(int* __restrict__ bsums, int nb) {
  __shared__ int a[128], b[128];
  int t = threadIdx.x;
  int v = (t < nb) ? bsums[t] : 0;
  a[t] = v;
  __syncthreads();
  int* s = a;
  int* d = b;
  for (int st = 1; st < 128; st <<= 1) {
    d[t] = s[t] + (t >= st ? s[t - st] : 0);
    __syncthreads();
    int* tp = s; s = d; d = tp;
  }
  if (t < nb) bsums[t] = s[t] - v;  // exclusive
}

__global__ __launch_bounds__(256) void k_scan_c(int* __restrict__ off,
                                                const int* __restrict__ bsums,
                                                int* __restrict__ cur) {
  int i = blockIdx.x * 256 + threadIdx.x;
  if (i < NN) {
    int o = off[i] + bsums[blockIdx.x];
    off[i] = o;
    cur[i] = o;  // cur aliases cnt (counts dead after scan)
  }
  if (i == 0) off[NN] = NE;
}

__global__ __launch_bounds__(256) void k_scatter(const int* __restrict__ src,
                                                 const int* __restrict__ dst,
                                                 int* __restrict__ cur,
                                                 int* __restrict__ srcs) {
  int e = blockIdx.x * 256 + threadIdx.x;
  if (e < NE) {
    int d = dst[e];
    int p = atomicAdd(&cur[d], 1);
    srcs[p] = src[e];
  }
}

// ============================ bf16 helpers ============================
__device__ __forceinline__ short f2b(float f) {  // RNE f32->bf16
  union { float f; unsigned u; } a;
  a.f = f;
  unsigned r = a.u + 0x7FFF + ((a.u >> 16) & 1);
  return (short)(r >> 16);
}

__device__ __forceinline__ bhalf8 load_a8(const float* __restrict__ p) {
  float4 x0 = *(const float4*)p;
  float4 x1 = *(const float4*)(p + 4);
  bhalf8 a;
  a[0] = f2b(x0.x); a[1] = f2b(x0.y); a[2] = f2b(x0.z); a[3] = f2b(x0.w);
  a[4] = f2b(x1.x); a[5] = f2b(x1.y); a[6] = f2b(x1.z); a[7] = f2b(x1.w);
  return a;
}

// convert the 4 weight matrices (each 128x128 f32) to bf16, packed [4][16384]
__global__ __launch_bounds__(256) void k_wconv(const float* __restrict__ W0,
                                               const float* __restrict__ W1,
                                               const float* __restrict__ W2,
                                               const float* __restrict__ W3,
                                               short* __restrict__ out) {
  int i = blockIdx.x * 256 + threadIdx.x;  // 65536 total
  int m = i >> 14;
  const float* src = (m == 0) ? W0 : (m == 1) ? W1 : (m == 2) ? W2 : W3;
  out[i] = f2b(src[i & 16383]);
}

// ============================ MFMA GEMM: O = X @ Wb^T + B ============================
// X f32 [*,128] (converted to bf16 in-register), Wb bf16 [128,128] row-major
// (out-col c uses Wb[c][:]), B f32 [128]. Block 256 = 4 waves; wave w owns
// rows [row_base + w*16, +16). mfma_f32_16x16x32_bf16:
//   A: row = lane&15, k = (lane>>4)*8 + j   (8 contiguous k per lane)
//   B: col = lane&15, k = (lane>>4)*8 + j
//   D: col = lane&15, row = (lane>>4)*4 + i
// In-place (O==X) safe: wave-private row window, loads consumed before stores.
__device__ __forceinline__ void gemm_mfma(const float* __restrict__ X,
                                          const short* __restrict__ Wb,
                                          const float* __restrict__ B,
                                          float* __restrict__ O, int row_base) {
  int lane = threadIdx.x & 63;
  int w = threadIdx.x >> 6;
  int rr = lane & 15;
  int g = lane >> 4;
  int arow = row_base + w * 16 + rr;
  floatx4 acc[8];
#pragma unroll
  for (int nt = 0; nt < 8; ++nt) acc[nt] = (floatx4){0.f, 0.f, 0.f, 0.f};
  const float* xrow = X + (size_t)arow * HID;
#pragma unroll
  for (int kt = 0; kt < 4; ++kt) {
    bhalf8 a;
    if (arow < NN) {
      a = load_a8(xrow + kt * 32 + g * 8);
    } else {
      a = (bhalf8){0, 0, 0, 0, 0, 0, 0, 0};
    }
#pragma unroll
    for (int nt = 0; nt < 8; ++nt) {
      bhalf8 b = *(const bhalf8*)(Wb + (nt * 16 + rr) * HID + kt * 32 + g * 8);
      acc[nt] = __builtin_amdgcn_mfma_f32_16x16x32_bf16(a, b, acc[nt], 0, 0, 0);
    }
  }
  int orow0 = row_base + w * 16 + g * 4;
#pragma unroll
  for (int nt = 0; nt < 8; ++nt) {
    int col = nt * 16 + rr;
    float bias = B[col];
#pragma unroll
    for (int i = 0; i < 4; ++i) {
      int r = orow0 + i;
      if (r < NN) O[(size_t)r * HID + col] = acc[nt][i] + bias;
    }
  }
}

__global__ __launch_bounds__(256) void k_proj(
    const float* __restrict__ q, const float* __restrict__ k,
    const float* __restrict__ v, const short* __restrict__ Wb,
    const float* __restrict__ bq, const float* __restrict__ bk,
    const float* __restrict__ bv, float* __restrict__ Q, float* __restrict__ K,
    float* __restrict__ V) {
  int row0 = blockIdx.x * 64;
  if (blockIdx.y == 0) gemm_mfma(q, Wb, bq, Q, row0);
  else if (blockIdx.y == 1) gemm_mfma(k, Wb + 16384, bk, K, row0);
  else gemm_mfma(v, Wb + 2 * 16384, bv, V, row0);
}

__global__ __launch_bounds__(256) void k_gemm(const float* __restrict__ X,
                                              const short* __restrict__ Wb,
                                              const float* __restrict__ B,
                                              float* __restrict__ O) {
  gemm_mfma(X, Wb + 3 * 16384, B, O, blockIdx.x * 64);
}

// ============================ edge attention ============================
// one thread per (node, head); 8 adjacent lanes = 8 heads of one node
__global__ __launch_bounds__(256) void k_edge(const int* __restrict__ off,
                                              const int* __restrict__ srcs,
                                              const float* __restrict__ Q,
                                              const float* __restrict__ K,
                                              const float* __restrict__ V,
                                              float* __restrict__ O) {
  int gid = blockIdx.x * 256 + threadIdx.x;
  if (gid >= NN * NH) return;
  int node = gid >> 3;
  int h = gid & 7;
  const float* qp = Q + node * HID + h * HD;
  float4 q0 = *(const float4*)(qp);
  float4 q1 = *(const float4*)(qp + 4);
  float4 q2 = *(const float4*)(qp + 8);
  float4 q3 = *(const float4*)(qp + 12);
  int i0 = off[node], i1 = off[node + 1];
  float m = -INFINITY, l = 0.f;
  float4 a0 = make_float4(0.f, 0.f, 0.f, 0.f);
  float4 a1 = a0, a2 = a0, a3 = a0;
  for (int i = i0; i < i1; ++i) {
    int s = srcs[i];
    const float* kp = K + s * HID + h * HD;
    float4 k0 = *(const float4*)(kp);
    float4 k1 = *(const float4*)(kp + 4);
    float4 k2 = *(const float4*)(kp + 8);
    float4 k3 = *(const float4*)(kp + 12);
    float dt = q0.x * k0.x + q0.y * k0.y + q0.z * k0.z + q0.w * k0.w +
               q1.x * k1.x + q1.y * k1.y + q1.z * k1.z + q1.w * k1.w +
               q2.x * k2.x + q2.y * k2.y + q2.z * k2.z + q2.w * k2.w +
               q3.x * k3.x + q3.y * k3.y + q3.z * k3.z + q3.w * k3.w;
    float sc = dt * ATT_SCALE;
    float nm = fmaxf(m, sc);
    float corr = __expf(m - nm);  // m=-inf first iter -> 0
    float p = __expf(sc - nm);
    m = nm;
    l = l * corr + p;
    const float* vp = V + s * HID + h * HD;
    float4 v0 = *(const float4*)(vp);
    float4 v1 = *(const float4*)(vp + 4);
    float4 v2 = *(const float4*)(vp + 8);
    float4 v3 = *(const float4*)(vp + 12);
    a0.x = a0.x * corr + p * v0.x; a0.y = a0.y * corr + p * v0.y;
    a0.z = a0.z * corr + p * v0.z; a0.w = a0.w * corr + p * v0.w;
    a1.x = a1.x * corr + p * v1.x; a1.y = a1.y * corr + p * v1.y;
    a1.z = a1.z * corr + p * v1.z; a1.w = a1.w * corr + p * v1.w;
    a2.x = a2.x * corr + p * v2.x; a2.y = a2.y * corr + p * v2.y;
    a2.z = a2.z * corr + p * v2.z; a2.w = a2.w * corr + p * v2.w;
    a3.x = a3.x * corr + p * v3.x; a3.y = a3.y * corr + p * v3.y;
    a3.z = a3.z * corr + p * v3.z; a3.w = a3.w * corr + p * v3.w;
  }
  float inv = 1.f / (l + 1e-8f);  // degree 0 -> acc 0 -> out 0 (matches ref)
  float* op = O + node * HID + h * HD;
  a0.x *= inv; a0.y *= inv; a0.z *= inv; a0.w *= inv;
  a1.x *= inv; a1.y *= inv; a1.z *= inv; a1.w *= inv;
  a2.x *= inv; a2.y *= inv; a2.z *= inv; a2.w *= inv;
  a3.x *= inv; a3.y *= inv; a3.z *= inv; a3.w *= inv;
  *(float4*)(op) = a0;
  *(float4*)(op + 4) = a1;
  *(float4*)(op + 8) = a2;
  *(float4*)(op + 12) = a3;
}

// ============================ launch ============================
extern "C" void kernel_launch(void* const* d_in, const int* in_sizes, int n_in,
                              void* d_out, int out_size, void* d_ws,
                              size_t ws_size, hipStream_t stream) {
  const float* q = (const float*)d_in[0];
  const float* k = (const float*)d_in[1];
  const float* v = (const float*)d_in[2];
  const int* ei = (const int*)d_in[3];
  const float* Wq = (const float*)d_in[4];
  const float* bq = (const float*)d_in[5];
  const float* Wk = (const float*)d_in[6];
  const float* bk = (const float*)d_in[7];
  const float* Wv = (const float*)d_in[8];
  const float* bv = (const float*)d_in[9];
  const float* Wo = (const float*)d_in[10];
  const float* bo = (const float*)d_in[11];
  const int* src = ei;
  const int* dst = ei + NE;

  int* cnt = (int*)d_ws;            // NN  (reused as scatter cursor)
  int* off = cnt + NN;              // NN + 4 (padded)
  int* bsums = off + NN + 4;        // 128
  int* srcs = bsums + 128;          // NE
  short* Wb = (short*)(srcs + NE);  // 4*16384 bf16
  float* Q = (float*)(Wb + 4 * 16384);  // NN*HID
  float* K = Q + NN * HID;
  float* V = K + NN * HID;
  float* O = (float*)d_out;

  hipMemsetAsync(cnt, 0, NN * sizeof(int), stream);
  k_wconv<<<256, 256, 0, stream>>>(Wq, Wk, Wv, Wo, Wb);
  k_hist<<<(NE + 255) / 256, 256, 0, stream>>>(dst, cnt);
  int nb = (NN + 255) / 256;  // 79
  k_scan_a<<<nb, 256, 0, stream>>>(cnt, off, bsums);
  k_scan_b<<<1, 128, 0, stream>>>(bsums, nb);
  k_scan_c<<<nb, 256, 0, stream>>>(off, bsums, cnt);  // cnt becomes cursor
  k_scatter<<<(NE + 255) / 256, 256, 0, stream>>>(src, dst, cnt, srcs);

  dim3 pg((NN + 63) / 64, 3);
  k_proj<<<pg, 256, 0, stream>>>(q, k, v, Wb, bq, bk, bv, Q, K, V);
  k_edge<<<(NN * NH + 255) / 256, 256, 0, stream>>>(off, srcs, Q, K, V, O);
  k_gemm<<<(NN + 63) / 64, 256, 0, stream>>>(O, Wb, bo, O);  // in-place safe
}

// Round 3
// 200.806 us; speedup vs baseline: 1.5953x; 1.2197x over previous
//
#include <hip/hip_runtime.h>
#include <math.h>

#define NN 20000
#define NE 640000
#define HID 128
#define NH 8
#define HD 16
#define ATT_SCALE 0.25f

typedef __attribute__((ext_vector_type(8))) short bhalf8;
typedef __attribute__((ext_vector_type(4))) float floatx4;

// ============================ CSR build ============================
__global__ __launch_bounds__(256) void k_hist(const int* __restrict__ dst,
                                              int* __restrict__ cnt) {
  int e = blockIdx.x * 256 + threadIdx.x;
  if (e < NE) atomicAdd(&cnt[dst[e]], 1);
}

__global__ __launch_bounds__(256) void k_scan_a(const int* __restrict__ cnt,
                                                int* __restrict__ off,
                                                int* __restrict__ bsums) {
  __shared__ int a[256], b[256];
  int t = threadIdx.x;
  int i = blockIdx.x * 256 + t;
  int v = (i < NN) ? cnt[i] : 0;
  a[t] = v;
  __syncthreads();
  int* s = a;
  int* d = b;
  for (int st = 1; st < 256; st <<= 1) {
    d[t] = s[t] + (t >= st ? s[t - st] : 0);
    __syncthreads();
    int* tp = s; s = d; d = tp;
  }
  if (i < NN) off[i] = s[t] - v;  // exclusive within block
  if (t == 255) bsums[blockIdx.x] = s[t];
}

__global__ __launch_bounds__(128) void k_scan_b(int* __restrict__ bsums, int nb) {
  __shared__ int a[128], b[128];
  int t = threadIdx.x;
  int v = (t < nb) ? bsums[t] : 0;
  a[t] = v;
  __syncthreads();
  int* s = a;
  int* d = b;
  for (int st = 1; st < 128; st <<= 1) {
    d[t] = s[t] + (t >= st ? s[t - st] : 0);
    __syncthreads();
    int* tp = s; s = d; d = tp;
  }
  if (t < nb) bsums[t] = s[t] - v;  // exclusive
}

__global__ __launch_bounds__(256) void k_scan_c(int* __restrict__ off,
                                                const int* __restrict__ bsums,
                                                int* __restrict__ cur) {
  int i = blockIdx.x * 256 + threadIdx.x;
  if (i < NN) {
    int o = off[i] + bsums[blockIdx.x];
    off[i] = o;
    cur[i] = o;  // cur aliases cnt (counts dead after scan)
  }
  if (i == 0) off[NN] = NE;
}

__global__ __launch_bounds__(256) void k_scatter(const int* __restrict__ src,
                                                 const int* __restrict__ dst,
                                                 int* __restrict__ cur,
                                                 int* __restrict__ srcs) {
  int e = blockIdx.x * 256 + threadIdx.x;
  if (e < NE) {
    int d = dst[e];
    int p = atomicAdd(&cur[d], 1);
    srcs[p] = src[e];
  }
}

// ============================ bf16 helpers ============================
__device__ __forceinline__ short f2b(float f) {  // RNE f32->bf16
  union { float f; unsigned u; } a;
  a.f = f;
  unsigned r = a.u + 0x7FFF + ((a.u >> 16) & 1);
  return (short)(r >> 16);
}

__device__ __forceinline__ float b2f(short s) {
  union { unsigned u; float f; } a;
  a.u = ((unsigned)(unsigned short)s) << 16;
  return a.f;
}

__device__ __forceinline__ bhalf8 load_a8(const float* __restrict__ p) {
  float4 x0 = *(const float4*)p;
  float4 x1 = *(const float4*)(p + 4);
  bhalf8 a;
  a[0] = f2b(x0.x); a[1] = f2b(x0.y); a[2] = f2b(x0.z); a[3] = f2b(x0.w);
  a[4] = f2b(x1.x); a[5] = f2b(x1.y); a[6] = f2b(x1.z); a[7] = f2b(x1.w);
  return a;
}

// convert the 4 weight matrices (each 128x128 f32) to bf16, packed [4][16384]
__global__ __launch_bounds__(256) void k_wconv(const float* __restrict__ W0,
                                               const float* __restrict__ W1,
                                               const float* __restrict__ W2,
                                               const float* __restrict__ W3,
                                               short* __restrict__ out) {
  int i = blockIdx.x * 256 + threadIdx.x;  // 65536 total
  int m = i >> 14;
  const float* src = (m == 0) ? W0 : (m == 1) ? W1 : (m == 2) ? W2 : W3;
  out[i] = f2b(src[i & 16383]);
}

// ============================ MFMA GEMM: O = X @ Wb^T + B ============================
// X f32 [*,128] (converted to bf16 in-register), Wb bf16 [128,128] row-major
// (out-col c uses Wb[c][:]), B f32 [128]. Block 256 = 4 waves; wave w owns
// rows [row_base + w*16, +16). mfma_f32_16x16x32_bf16:
//   A: row = lane&15, k = (lane>>4)*8 + j   (8 contiguous k per lane)
//   B: col = lane&15, k = (lane>>4)*8 + j
//   D: col = lane&15, row = (lane>>4)*4 + i
// In-place (O==X) safe: wave-private row window, loads consumed before stores.
template <bool OUT_BF16>
__device__ __forceinline__ void gemm_mfma(const float* __restrict__ X,
                                          const short* __restrict__ Wb,
                                          const float* __restrict__ B,
                                          void* __restrict__ O, int row_base) {
  int lane = threadIdx.x & 63;
  int w = threadIdx.x >> 6;
  int rr = lane & 15;
  int g = lane >> 4;
  int arow = row_base + w * 16 + rr;
  floatx4 acc[8];
#pragma unroll
  for (int nt = 0; nt < 8; ++nt) acc[nt] = (floatx4){0.f, 0.f, 0.f, 0.f};
  const float* xrow = X + (size_t)arow * HID;
#pragma unroll
  for (int kt = 0; kt < 4; ++kt) {
    bhalf8 a;
    if (arow < NN) {
      a = load_a8(xrow + kt * 32 + g * 8);
    } else {
      a = (bhalf8){0, 0, 0, 0, 0, 0, 0, 0};
    }
#pragma unroll
    for (int nt = 0; nt < 8; ++nt) {
      bhalf8 b = *(const bhalf8*)(Wb + (nt * 16 + rr) * HID + kt * 32 + g * 8);
      acc[nt] = __builtin_amdgcn_mfma_f32_16x16x32_bf16(a, b, acc[nt], 0, 0, 0);
    }
  }
  int orow0 = row_base + w * 16 + g * 4;
#pragma unroll
  for (int nt = 0; nt < 8; ++nt) {
    int col = nt * 16 + rr;
    float bias = B[col];
#pragma unroll
    for (int i = 0; i < 4; ++i) {
      int r = orow0 + i;
      if (r < NN) {
        float val = acc[nt][i] + bias;
        if (OUT_BF16)
          ((short*)O)[(size_t)r * HID + col] = f2b(val);
        else
          ((float*)O)[(size_t)r * HID + col] = val;
      }
    }
  }
}

__global__ __launch_bounds__(256) void k_proj(
    const float* __restrict__ q, const float* __restrict__ k,
    const float* __restrict__ v, const short* __restrict__ Wb,
    const float* __restrict__ bq, const float* __restrict__ bk,
    const float* __restrict__ bv, short* __restrict__ Qb,
    short* __restrict__ Kb, short* __restrict__ Vb) {
  int row0 = blockIdx.x * 64;
  if (blockIdx.y == 0) gemm_mfma<true>(q, Wb, bq, Qb, row0);
  else if (blockIdx.y == 1) gemm_mfma<true>(k, Wb + 16384, bk, Kb, row0);
  else gemm_mfma<true>(v, Wb + 2 * 16384, bv, Vb, row0);
}

__global__ __launch_bounds__(256) void k_gemm(const float* __restrict__ X,
                                              const short* __restrict__ Wb,
                                              const float* __restrict__ B,
                                              float* __restrict__ O) {
  gemm_mfma<false>(X, Wb + 3 * 16384, B, O, blockIdx.x * 64);
}

// ============================ edge attention ============================
// 4 lanes per (node, head): lane = h + 8*j within a 32-lane node group.
// Each lane processes edges i0+j, i0+j+4, ... with a private online-softmax
// partial; partials merged via shfl_xor(8), shfl_xor(16). 8 head-lanes of a
// segment read one contiguous 256 B bf16 K/V row slice (coalesced).
__global__ __launch_bounds__(256, 8) void k_edge(
    const int* __restrict__ off, const int* __restrict__ srcs,
    const short* __restrict__ Qb, const short* __restrict__ Kb,
    const short* __restrict__ Vb, float* __restrict__ O) {
  int gid = blockIdx.x * 256 + threadIdx.x;  // exactly NN*32 threads
  int node = gid >> 5;
  int sub = gid & 31;
  int h = sub & 7;
  int j = sub >> 3;
  const short* qp = Qb + node * HID + h * HD;
  bhalf8 q0 = *(const bhalf8*)qp;        // Q kept packed: 8 VGPRs
  bhalf8 q1 = *(const bhalf8*)(qp + 8);
  int i0 = off[node], i1 = off[node + 1];
  float m = -1e30f, l = 0.f;
  float acc[16];
#pragma unroll
  for (int t = 0; t < 16; ++t) acc[t] = 0.f;
  for (int i = i0 + j; i < i1; i += 4) {
    int s = srcs[i];
    const short* kp = Kb + s * HID + h * HD;
    bhalf8 k0 = *(const bhalf8*)kp;
    bhalf8 k1 = *(const bhalf8*)(kp + 8);
    const short* vp = Vb + s * HID + h * HD;
    bhalf8 v0 = *(const bhalf8*)vp;
    bhalf8 v1 = *(const bhalf8*)(vp + 8);
    float d0 = 0.f, d1 = 0.f;
#pragma unroll
    for (int t = 0; t < 8; ++t) d0 += b2f(q0[t]) * b2f(k0[t]);
#pragma unroll
    for (int t = 0; t < 8; ++t) d1 += b2f(q1[t]) * b2f(k1[t]);
    float sc = (d0 + d1) * ATT_SCALE;
    float nm = fmaxf(m, sc);
    float corr = __expf(m - nm);  // m=-1e30 first iter -> underflow 0
    float p = __expf(sc - nm);
    m = nm;
    l = l * corr + p;
#pragma unroll
    for (int t = 0; t < 8; ++t) acc[t] = acc[t] * corr + p * b2f(v0[t]);
#pragma unroll
    for (int t = 0; t < 8; ++t) acc[t + 8] = acc[t + 8] * corr + p * b2f(v1[t]);
  }
  // merge 4 segment partials (lanes h, h+8, h+16, h+24)
#pragma unroll
  for (int mask = 8; mask <= 16; mask <<= 1) {
    float m2 = __shfl_xor(m, mask, 64);
    float l2 = __shfl_xor(l, mask, 64);
    float nm = fmaxf(m, m2);
    float c1 = __expf(m - nm);   // both empty: exp(0)=1, l=0 -> harmless
    float c2 = __expf(m2 - nm);
    l = l * c1 + l2 * c2;
#pragma unroll
    for (int t = 0; t < 16; ++t) {
      float a2 = __shfl_xor(acc[t], mask, 64);
      acc[t] = acc[t] * c1 + a2 * c2;
    }
    m = nm;
  }
  float inv = 1.f / (l + 1e-8f);  // degree 0 -> acc 0 -> out 0 (matches ref)
  // lane j writes quarter [4j, 4j+4) — compile-time indices only (no scratch)
  float4 o;
  if (j == 0)      o = make_float4(acc[0],  acc[1],  acc[2],  acc[3]);
  else if (j == 1) o = make_float4(acc[4],  acc[5],  acc[6],  acc[7]);
  else if (j == 2) o = make_float4(acc[8],  acc[9],  acc[10], acc[11]);
  else             o = make_float4(acc[12], acc[13], acc[14], acc[15]);
  o.x *= inv; o.y *= inv; o.z *= inv; o.w *= inv;
  *(float4*)(O + node * HID + h * HD + j * 4) = o;
}

// ============================ launch ============================
extern "C" void kernel_launch(void* const* d_in, const int* in_sizes, int n_in,
                              void* d_out, int out_size, void* d_ws,
                              size_t ws_size, hipStream_t stream) {
  const float* q = (const float*)d_in[0];
  const float* k = (const float*)d_in[1];
  const float* v = (const float*)d_in[2];
  const int* ei = (const int*)d_in[3];
  const float* Wq = (const float*)d_in[4];
  const float* bq = (const float*)d_in[5];
  const float* Wk = (const float*)d_in[6];
  const float* bk = (const float*)d_in[7];
  const float* Wv = (const float*)d_in[8];
  const float* bv = (const float*)d_in[9];
  const float* Wo = (const float*)d_in[10];
  const float* bo = (const float*)d_in[11];
  const int* src = ei;
  const int* dst = ei + NE;

  int* cnt = (int*)d_ws;            // NN  (reused as scatter cursor)
  int* off = cnt + NN;              // NN + 4 (padded)
  int* bsums = off + NN + 4;        // 128
  int* srcs = bsums + 128;          // NE
  short* Wb = (short*)(srcs + NE);  // 4*16384 bf16
  short* Qb = Wb + 4 * 16384;       // NN*HID bf16
  short* Kb = Qb + NN * HID;
  short* Vb = Kb + NN * HID;
  float* O = (float*)d_out;

  hipMemsetAsync(cnt, 0, NN * sizeof(int), stream);
  k_wconv<<<256, 256, 0, stream>>>(Wq, Wk, Wv, Wo, Wb);
  k_hist<<<(NE + 255) / 256, 256, 0, stream>>>(dst, cnt);
  int nb = (NN + 255) / 256;  // 79
  k_scan_a<<<nb, 256, 0, stream>>>(cnt, off, bsums);
  k_scan_b<<<1, 128, 0, stream>>>(bsums, nb);
  k_scan_c<<<nb, 256, 0, stream>>>(off, bsums, cnt);  // cnt becomes cursor
  k_scatter<<<(NE + 255) / 256, 256, 0, stream>>>(src, dst, cnt, srcs);

  dim3 pg((NN + 63) / 64, 3);
  k_proj<<<pg, 256, 0, stream>>>(q, k, v, Wb, bq, bk, bv, Qb, Kb, Vb);
  k_edge<<<(NN * 32) / 256, 256, 0, stream>>>(off, srcs, Qb, Kb, Vb, O);
  k_gemm<<<(NN + 63) / 64, 256, 0, stream>>>(O, Wb, bo, O);  // in-place safe
}